// Round 6
// baseline (565.054 us; speedup 1.0000x reference)
//
#include <hip/hip_runtime.h>
#include <math.h>

#define N_ 2
#define A_ 5
#define C_ 12
#define H_ 256
#define G_ 512
// out = 4 * ifft_ortho(K * fft_ortho(...)) ==> 4/(512*512) on unnormalized FFTs
#define SCALE_ (4.0f / 262144.0f)
#define OUTF_ 655360       // out = fp32 REAL part, [2,5,256,256]
#define HALFF_ 327680      // per-n float count
#define IMGC_ 131072       // 512*256 complex: one spectral half-plane (h2 elems)

// ---- fp16-pair scratch ------------------------------------------------------
struct __attribute__((aligned(4))) h2 { _Float16 x, y; };
__device__ __forceinline__ float2 ld2(const h2* p, size_t i) {
    h2 v = p[i]; return make_float2((float)v.x, (float)v.y);
}
__device__ __forceinline__ void st2(h2* p, size_t i, float2 v) {
    float x = fminf(fmaxf(v.x, -60000.f), 60000.f);   // never store inf
    float y = fminf(fmaxf(v.y, -60000.f), 60000.f);
    h2 o; o.x = (_Float16)x; o.y = (_Float16)y; p[i] = o;
}

__device__ __forceinline__ float2 cmul(float2 a, float2 b) {
    return make_float2(a.x * b.x - a.y * b.y, a.x * b.y + a.y * b.x);
}

// ---- float4 = two adjacent complexes helpers (A2/C2 radix-4 path) -----------
__device__ __forceinline__ float4 qadd(float4 a, float4 b) {
    return make_float4(a.x + b.x, a.y + b.y, a.z + b.z, a.w + b.w);
}
__device__ __forceinline__ float4 qsub(float4 a, float4 b) {
    return make_float4(a.x - b.x, a.y - b.y, a.z - b.z, a.w - b.w);
}
__device__ __forceinline__ float4 qmul(float4 a, float4 w) {   // per-complex a*w
    return make_float4(a.x * w.x - a.y * w.y, a.x * w.y + a.y * w.x,
                       a.z * w.z - a.w * w.w, a.z * w.w + a.w * w.z);
}
__device__ __forceinline__ float4 qmulc(float4 a, float4 w) {  // per-complex a*conj(w)
    return make_float4(a.x * w.x + a.y * w.y, a.y * w.x - a.x * w.y,
                       a.z * w.z + a.w * w.w, a.w * w.z - a.z * w.w);
}
// f4-index bank swizzle: bijective within 8-blocks, kills stride-4/16 conflicts
__device__ __forceinline__ int PHI(int i) { return i ^ ((i >> 3) & 7); }

// Per-stage twiddle tables, float2 twS[512]:
//   stage half-size m occupies f2 [off, off+m), off = 0,256,384,448,480,496,
//   504,508,510; entry j = w^(j*(256/m)), w = exp(-2pi i/512).
__device__ __forceinline__ void build_twS(float2* twS, int t) {
    if (t < 256) {
        float s, c;
        sincosf(-6.283185307179586f * (float)t * (1.0f / 512.0f), &s, &c);
        twS[t] = make_float2(c, s);
    }
    __syncthreads();
    int off = 256;
    #pragma unroll
    for (int sh = 1; sh <= 8; sh++) {
        int sz = 256 >> sh;
        if (t < sz) twS[off + t] = twS[t << sh];
        off += sz;
    }
    __syncthreads();
}

// ---- register + shuffle 512-pt FFT (one wave, 8 complexes/lane) -------------
// position i = s*64 + l; storage index i holds freq brev9(i) after forward.
__device__ __forceinline__ float2 shflx2(float2 v, int m) {
    return make_float2(__shfl_xor(v.x, m, 64), __shfl_xor(v.y, m, 64));
}
__device__ __forceinline__ void BFF(float2& A, float2& B, float2 W) {
    float2 a = A;
    A = make_float2(a.x + B.x, a.y + B.y);
    B = cmul(make_float2(a.x - B.x, a.y - B.y), W);
}
__device__ __forceinline__ void BFI(float2& A, float2& B, float2 W) {
    float2 b = make_float2(B.x * W.x + B.y * W.y, B.y * W.x - B.x * W.y); // B*conj(W)
    float2 a = A;
    A = make_float2(a.x + b.x, a.y + b.y);
    B = make_float2(a.x - b.x, a.y - b.y);
}

__device__ __forceinline__ void fwd512_reg(float2* v, const float2* twS, int l) {
    // reg stages m=256,128,64 (j = i&(m-1))
    {
        float2 w0 = twS[l], w1 = twS[64 + l], w2 = twS[128 + l], w3 = twS[192 + l];
        BFF(v[0], v[4], w0); BFF(v[1], v[5], w1);
        BFF(v[2], v[6], w2); BFF(v[3], v[7], w3);
        float2 u0 = twS[256 + l], u1 = twS[320 + l];
        BFF(v[0], v[2], u0); BFF(v[1], v[3], u1);
        BFF(v[4], v[6], u0); BFF(v[5], v[7], u1);
        float2 z = twS[384 + l];
        BFF(v[0], v[1], z); BFF(v[2], v[3], z);
        BFF(v[4], v[5], z); BFF(v[6], v[7], z);
    }
    // shuffle stages m=32..1 (partner lane l^m; j = l&(m-1), same for all s)
    const int offs[6] = {448, 480, 496, 504, 508, 510};
    const int ms[6]   = {32, 16, 8, 4, 2, 1};
    #pragma unroll
    for (int st = 0; st < 6; st++) {
        int m = ms[st];
        float2 w = twS[offs[st] + (l & (m - 1))];
        bool up = (l & m) != 0;
        float sgn = up ? -1.f : 1.f;
        float2 we = up ? w : make_float2(1.f, 0.f);
        #pragma unroll
        for (int s = 0; s < 8; s++) {
            float2 o = shflx2(v[s], m);
            // lower: v+o ; upper: (o-v)*w
            float2 d = make_float2(fmaf(sgn, v[s].x, o.x), fmaf(sgn, v[s].y, o.y));
            v[s] = cmul(d, we);
        }
    }
}

__device__ __forceinline__ void inv512_reg(float2* v, const float2* twS, int l) {
    const int offs[6] = {510, 508, 504, 496, 480, 448};
    const int ms[6]   = {1, 2, 4, 8, 16, 32};
    #pragma unroll
    for (int st = 0; st < 6; st++) {
        int m = ms[st];
        float2 w = twS[offs[st] + (l & (m - 1))];
        bool up = (l & m) != 0;
        float sgn = up ? -1.f : 1.f;
        // upper premultiplies its value by conj(w); exchange; res = sgn*u + o
        float2 wc = up ? make_float2(w.x, -w.y) : make_float2(1.f, 0.f);
        #pragma unroll
        for (int s = 0; s < 8; s++) {
            float2 u = cmul(v[s], wc);
            float2 o = shflx2(u, m);
            v[s] = make_float2(fmaf(sgn, u.x, o.x), fmaf(sgn, u.y, o.y));
        }
    }
    // reg stages m=64,128,256
    {
        float2 z = twS[384 + l];
        BFI(v[0], v[1], z); BFI(v[2], v[3], z);
        BFI(v[4], v[5], z); BFI(v[6], v[7], z);
        float2 u0 = twS[256 + l], u1 = twS[320 + l];
        BFI(v[0], v[2], u0); BFI(v[1], v[3], u1);
        BFI(v[4], v[6], u0); BFI(v[5], v[7], u1);
        float2 w0 = twS[l], w1 = twS[64 + l], w2 = twS[128 + l], w3 = twS[192 + l];
        BFI(v[0], v[4], w0); BFI(v[1], v[5], w1);
        BFI(v[2], v[6], w2); BFI(v[3], v[7], w3);
    }
}

// ---- A2/C2 radix-4 LDS quads (unchanged, proven R5) -------------------------
__device__ __forceinline__ void fwd_quad(float4* D, const float4* tw4,
                                         int bt, int M4, int offA4) {
    int jf = bt & (M4 - 1);
    int f0 = ((bt & ~(M4 - 1)) << 2) | jf;
    float4 x0 = D[PHI(f0)],          x1 = D[PHI(f0 + M4)];
    float4 x2 = D[PHI(f0 + 2 * M4)], x3 = D[PHI(f0 + 3 * M4)];
    float4 tA  = tw4[offA4 + jf];
    float4 tA2 = tw4[offA4 + M4 + jf];
    float4 tB  = tw4[offA4 + 2 * M4 + jf];
    float4 u0 = qadd(x0, x2), v0 = qmul(qsub(x0, x2), tA);
    float4 u1 = qadd(x1, x3), v1 = qmul(qsub(x1, x3), tA2);
    D[PHI(f0)]          = qadd(u0, u1);
    D[PHI(f0 + M4)]     = qmul(qsub(u0, u1), tB);
    D[PHI(f0 + 2 * M4)] = qadd(v0, v1);
    D[PHI(f0 + 3 * M4)] = qmul(qsub(v0, v1), tB);
}
__device__ __forceinline__ void inv_quad(float4* D, const float4* tw4,
                                         int bt, int M2, int offM4, int off2M4) {
    int jf = bt & (M2 - 1);
    int f0 = ((bt & ~(M2 - 1)) << 2) | jf;
    float4 x0 = D[PHI(f0)],          x1 = D[PHI(f0 + M2)];
    float4 x2 = D[PHI(f0 + 2 * M2)], x3 = D[PHI(f0 + 3 * M2)];
    float4 wA  = tw4[offM4 + jf];
    float4 wB0 = tw4[off2M4 + jf];
    float4 wB1 = tw4[off2M4 + M2 + jf];
    float4 t1 = qmulc(x1, wA), t3 = qmulc(x3, wA);
    float4 u0 = qadd(x0, t1), u1 = qsub(x0, t1);
    float4 u2 = qadd(x2, t3), u3 = qsub(x2, t3);
    float4 s2 = qmulc(u2, wB0), s3 = qmulc(u3, wB1);
    D[PHI(f0)]          = qadd(u0, s2);
    D[PHI(f0 + M2)]     = qadd(u1, s3);
    D[PHI(f0 + 2 * M2)] = qsub(u0, s2);
    D[PHI(f0 + 3 * M2)] = qsub(u1, s3);
}

// ---- legacy single-array radix-2 FFTs (fallback path only) ------------------
__device__ void fft512_dif(float2* d, const float2* twS, int t) {
    int off = 0;
    #pragma unroll
    for (int m = 256; m >= 1; m >>= 1) {
        if (m >= 64) __syncthreads();
        else __builtin_amdgcn_wave_barrier();
        int j = t & (m - 1);
        int p = ((t & ~(m - 1)) << 1) | j;
        int q = p + m;
        float2 a = d[p], b = d[q];
        d[p] = make_float2(a.x + b.x, a.y + b.y);
        float2 s = make_float2(a.x - b.x, a.y - b.y);
        d[q] = cmul(s, twS[off + j]);
        off += m;
    }
    __syncthreads();
}
__device__ void ifft512_dit(float2* d, const float2* twS, int t) {
    int off = 510;
    #pragma unroll
    for (int m = 1; m <= 256; m <<= 1) {
        if (m == 1 || m >= 128) __syncthreads();
        else __builtin_amdgcn_wave_barrier();
        int j = t & (m - 1);
        int p = ((t & ~(m - 1)) << 1) | j;
        int q = p + m;
        float2 w = twS[off + j];
        w.y = -w.y;
        float2 b = cmul(d[q], w);
        float2 a = d[p];
        d[p] = make_float2(a.x + b.x, a.y + b.y);
        d[q] = make_float2(a.x - b.x, a.y - b.y);
        off -= (m << 1);
    }
    __syncthreads();
}

// ---- zero a float range of out ---------------------------------------------
__global__ __launch_bounds__(256)
void zeroF(float* outf, int base) {
    outf[(size_t)base + blockIdx.x * 256 + threadIdx.x] = 0.f;
}

// ===========================================================================
// FAST PATH (needs d_ws >= 58 MB)
// ===========================================================================

// R: Krev[p][h][jw] = K[p][h][brev9(jw)], p = b*5+a. grid(25*512).
// Direct bit-reversed gather (2 KB row stays in L1), coalesced stores;
// no LDS (old LDS read pattern was a 32-way bank conflict).
__global__ __launch_bounds__(256)
void kernelR(const float* __restrict__ kr, const float* __restrict__ ki,
             h2* Krev) {
    int p = blockIdx.x >> 9;
    int h = blockIdx.x & 511;
    int t = threadIdx.x;
    size_t base = ((size_t)p * G_ + h) * G_;
    int j0 = __brev((unsigned)t) >> 23;
    int j1 = __brev((unsigned)(t + 256)) >> 23;
    st2(Krev, base + t,       make_float2(kr[base + j0], ki[base + j0]));
    st2(Krev, base + t + 256, make_float2(kr[base + j1], ki[base + j1]));
}

// A2: x*mps, pad h, fwd FFT_h (radix-4 f4, wave owns 2 rows, mm=1 fused into
// transposed store), store to P[c*5+a]. grid(12*5*32), 256 thr.
__global__ __launch_bounds__(256)
void kernelA2(const float* __restrict__ xr, const float* __restrict__ xi,
              const float* __restrict__ mr, const float* __restrict__ mi,
              h2* P, int n) {
    int oct = blockIdx.x & 31;
    int a   = (blockIdx.x >> 5) % 5;
    int c   = blockIdx.x / 160;
    int t = threadIdx.x;
    __shared__ float2 twS[512];
    __shared__ float4 rows4[8][262];
    build_twS(twS, t);
    const float4* tw4 = (const float4*)twS;

    int r = t & 7;
    int wc = oct * 8 + r;
    float2* rowf2 = (float2*)&rows4[r][0];
    #pragma unroll
    for (int k = 0; k < 8; k++) {
        int h = (t >> 3) + 32 * k;
        size_t xo = (((size_t)n * A_ + a) * H_ + h) * H_ + wc;
        size_t mo = (((size_t)c) * H_ + h) * H_ + wc;
        float xr_ = xr[xo], xi_ = xi[xo];
        float mr_ = mr[mo], mi_ = mi[mo];
        int e = h + 128;
        rowf2[2 * PHI(e >> 1) + (e & 1)] =
            make_float2(xr_ * mr_ - xi_ * mi_, xr_ * mi_ + xi_ * mr_);
        int z = (h < 128) ? h : (h + 256);
        rowf2[2 * PHI(z >> 1) + (z & 1)] = make_float2(0.f, 0.f);
    }
    __syncthreads();

    int wv = t >> 6, ln = t & 63;
    float4* d0 = &rows4[2 * wv][0];
    float4* d1 = &rows4[2 * wv + 1][0];
    fwd_quad(d0, tw4, ln, 64, 0);   fwd_quad(d1, tw4, ln, 64, 0);
    __builtin_amdgcn_wave_barrier();
    fwd_quad(d0, tw4, ln, 16, 192); fwd_quad(d1, tw4, ln, 16, 192);
    __builtin_amdgcn_wave_barrier();
    fwd_quad(d0, tw4, ln, 4, 240);  fwd_quad(d1, tw4, ln, 4, 240);
    __builtin_amdgcn_wave_barrier();
    fwd_quad(d0, tw4, ln, 1, 252);  fwd_quad(d1, tw4, ln, 1, 252);
    __syncthreads();

    h2* Pp = P + (size_t)(c * 5 + a) * IMGC_;
    #pragma unroll
    for (int k = 0; k < 16; k++) {
        int jh = k * 32 + (t >> 3);
        float4 v = rows4[r][PHI(jh >> 1)];
        float2 res = (jh & 1) ? make_float2(v.x - v.z, v.y - v.w)
                              : make_float2(v.x + v.z, v.y + v.w);
        st2(Pp, (size_t)jh * 256 + oct * 8 + r, res);
    }
}

// B2: 320 thr, wave w owns array a=w (load + fwd reg/shuffle FFT), publishes
// its spectrum to LDS, then computes G[b=w] = sum_a Krev[w,a]*F[a] in regs,
// inverse reg/shuffle FFT, crop, store. ONE data barrier per block.
// grid 6144 = 8 XCD chunks x (64 jh x 12 c).
__global__ __launch_bounds__(320)
void kernelB2(const h2* __restrict__ Krev, h2* P) {
    int blk = blockIdx.x;
    int xcd = blk & 7;
    int idx = blk >> 3;
    int jh  = xcd * 64 + idx / 12;
    int c   = idx % 12;
    int htrue = __brev((unsigned)jh) >> 23;
    int t = threadIdx.x;
    int wv = t >> 6, l = t & 63;
    __shared__ float2 twS[512];
    __shared__ float2 Fs[5][512];
    build_twS(twS, t);

    // load own array a=wv, centered w-pad; reg layout: position i = s*64+l
    float2 v[8];
    const h2* Pa = P + (size_t)(c * 5 + wv) * IMGC_ + (size_t)jh * 256;
    v[0] = v[1] = v[6] = v[7] = make_float2(0.f, 0.f);
    #pragma unroll
    for (int s = 2; s <= 5; s++) v[s] = ld2(Pa, (s - 2) * 64 + l);

    fwd512_reg(v, twS, l);

    #pragma unroll
    for (int s = 0; s < 8; s++) Fs[wv][s * 64 + l] = v[s];
    __syncthreads();   // all spectra visible

    // mix: wave wv computes G[b=wv] at jw = s*64+l
    float2 g[8];
    #pragma unroll
    for (int s = 0; s < 8; s++) g[s] = make_float2(0.f, 0.f);
    #pragma unroll
    for (int a = 0; a < 5; a++) {
        size_t kb = ((size_t)(wv * 5 + a) * G_ + htrue) * G_;
        #pragma unroll
        for (int s = 0; s < 8; s++) {
            float2 f = Fs[a][s * 64 + l];
            float2 kv = ld2(Krev, kb + s * 64 + l);
            g[s].x += kv.x * f.x - kv.y * f.y;
            g[s].y += kv.x * f.y + kv.y * f.x;
        }
    }

    inv512_reg(g, twS, l);

    // crop w (positions 128..383 = s=2..5), store b=wv in place
    h2* Pb = P + (size_t)(c * 5 + wv) * IMGC_ + (size_t)jh * 256;
    #pragma unroll
    for (int s = 2; s <= 5; s++) st2(Pb, (s - 2) * 64 + l, g[s]);
}

// C2: inv FFT_h of P[c*5+b] (radix-4 f4, wave owns 2 rows, mm=1 fused into
// load), crop h, Re(conj(mps)*y)*scale, fp32 atomics. grid(12*5*32), 256 thr.
__global__ __launch_bounds__(256)
void kernelC2(const float* __restrict__ mr, const float* __restrict__ mi,
              const h2* __restrict__ P, float* outf, int n) {
    int oct = blockIdx.x & 31;
    int b   = (blockIdx.x >> 5) % 5;
    int c   = blockIdx.x / 160;
    int t = threadIdx.x;
    __shared__ float2 twS[512];
    __shared__ float4 rows4[8][262];
    build_twS(twS, t);
    const float4* tw4 = (const float4*)twS;

    int r = t & 7;
    int wc = oct * 8 + r;
    const h2* Pb = P + (size_t)(c * 5 + b) * IMGC_;
    #pragma unroll
    for (int k = 0; k < 8; k++) {
        int jh0 = k * 64 + (t >> 3) * 2;
        float2 p0 = ld2(Pb, (size_t)jh0 * 256 + wc);
        float2 p1 = ld2(Pb, (size_t)(jh0 + 1) * 256 + wc);
        rows4[r][PHI(jh0 >> 1)] =
            make_float4(p0.x + p1.x, p0.y + p1.y, p0.x - p1.x, p0.y - p1.y);
    }
    __syncthreads();

    int wv = t >> 6, ln = t & 63;
    float4* d0 = &rows4[2 * wv][0];
    float4* d1 = &rows4[2 * wv + 1][0];
    inv_quad(d0, tw4, ln, 1, 254, 252);  inv_quad(d1, tw4, ln, 1, 254, 252);
    __builtin_amdgcn_wave_barrier();
    inv_quad(d0, tw4, ln, 4, 248, 240);  inv_quad(d1, tw4, ln, 4, 248, 240);
    __builtin_amdgcn_wave_barrier();
    inv_quad(d0, tw4, ln, 16, 224, 192); inv_quad(d1, tw4, ln, 16, 224, 192);
    __builtin_amdgcn_wave_barrier();
    inv_quad(d0, tw4, ln, 64, 128, 0);   inv_quad(d1, tw4, ln, 64, 128, 0);
    __syncthreads();

    const float2* rowf2 = (const float2*)&rows4[r][0];
    #pragma unroll
    for (int k = 0; k < 8; k++) {
        int hh = (t >> 3) + 32 * k;
        int e = hh + 128;
        float2 v = rowf2[2 * PHI(e >> 1) + (e & 1)];
        size_t mo = (((size_t)c) * H_ + hh) * H_ + wc;
        float m_r = mr[mo], m_i = mi[mo];
        float re = (m_r * v.x + m_i * v.y) * SCALE_;
        size_t idx = (((size_t)n * A_ + b) * H_ + hh) * H_ + wc;
        unsafeAtomicAdd(&outf[idx], re);
    }
}

// ===========================================================================
// FALLBACK PATH (used when ws_size < 58 MB)
// ===========================================================================

__global__ __launch_bounds__(256)
void kernelA(const float* __restrict__ xr, const float* __restrict__ xi,
             const float* __restrict__ mr, const float* __restrict__ mi,
             h2* X1, int n, int c, int a) {
    int oct = blockIdx.x;
    int t = threadIdx.x;
    __shared__ float2 twS[512];
    __shared__ float2 rows[8][516];
    build_twS(twS, t);

    int r = t & 7;
    int wc = oct * 8 + r;
    #pragma unroll
    for (int k = 0; k < 8; k++) {
        int h = (t >> 3) + 32 * k;
        size_t xo = (((size_t)n * A_ + a) * H_ + h) * H_ + wc;
        size_t mo = (((size_t)c) * H_ + h) * H_ + wc;
        float xr_ = xr[xo], xi_ = xi[xo];
        float mr_ = mr[mo], mi_ = mi[mo];
        rows[r][h + 128] = make_float2(xr_ * mr_ - xi_ * mi_,
                                       xr_ * mi_ + xi_ * mr_);
        rows[r][(h < 128) ? h : (h + 256)] = make_float2(0.f, 0.f);
    }
    __syncthreads();
    for (int rr = 0; rr < 8; rr++) fft512_dif(&rows[rr][0], twS, t);

    #pragma unroll
    for (int k = 0; k < 16; k++) {
        int jh = k * 32 + (t >> 3);
        st2(X1, (size_t)jh * 256 + oct * 8 + (t & 7), rows[t & 7][jh]);
    }
}

__global__ __launch_bounds__(256)
void kernelB(const float* __restrict__ kr, const float* __restrict__ ki,
             const h2* X1, h2* X2, int b, int a) {
    int jh = blockIdx.x;
    int htrue = __brev((unsigned)jh) >> 23;
    int t = threadIdx.x;
    __shared__ float2 twS[512];
    __shared__ float2 F[512];
    __shared__ float2 g[512];
    build_twS(twS, t);

    float2 v = ld2(X1, (size_t)jh * 256 + t);
    F[t + 128] = v;
    F[(t < 128) ? t : (t + 256)] = make_float2(0.f, 0.f);
    __syncthreads();
    fft512_dif(F, twS, t);

    #pragma unroll
    for (int half = 0; half < 2; half++) {
        int jw = t + half * 256;
        int wtrue = __brev((unsigned)jw) >> 23;
        size_t kidx = (((size_t)(b * A_ + a)) * G_ + htrue) * G_ + wtrue;
        g[jw] = cmul(make_float2(kr[kidx], ki[kidx]), F[jw]);
    }
    ifft512_dit(g, twS, t);

    float2 res = g[t + 128];
    size_t o = (size_t)jh * 256 + t;
    if (a == 0) st2(X2, o, res);
    else {
        float2 cur = ld2(X2, o);
        st2(X2, o, make_float2(cur.x + res.x, cur.y + res.y));
    }
}

__global__ __launch_bounds__(256)
void kernelC(const float* __restrict__ mr, const float* __restrict__ mi,
             const h2* X2, float* outf, int n, int c, int b) {
    int oct = blockIdx.x;
    int t = threadIdx.x;
    __shared__ float2 twS[512];
    __shared__ float2 rows[8][516];
    build_twS(twS, t);

    #pragma unroll
    for (int k = 0; k < 16; k++) {
        int jh = k * 32 + (t >> 3);
        rows[t & 7][jh] = ld2(X2, (size_t)jh * 256 + oct * 8 + (t & 7));
    }
    for (int rr = 0; rr < 8; rr++) ifft512_dit(&rows[rr][0], twS, t);

    int r = t & 7;
    int wc = oct * 8 + r;
    #pragma unroll
    for (int k = 0; k < 8; k++) {
        int hh = (t >> 3) + 32 * k;
        float2 v = rows[r][hh + 128];
        size_t mo = (((size_t)c) * H_ + hh) * H_ + wc;
        float m_r = mr[mo], m_i = mi[mo];
        float re = (m_r * v.x + m_i * v.y) * SCALE_;
        size_t idx = (((size_t)n * A_ + b) * H_ + hh) * H_ + wc;
        outf[idx] += re;
    }
}

// ===========================================================================
extern "C" void kernel_launch(void* const* d_in, const int* in_sizes, int n_in,
                              void* d_out, int out_size, void* d_ws, size_t ws_size,
                              hipStream_t stream) {
    const float* xr = (const float*)d_in[0];
    const float* xi = (const float*)d_in[1];
    const float* mr = (const float*)d_in[2];
    const float* mi = (const float*)d_in[3];
    const float* kr = (const float*)d_in[4];
    const float* ki = (const float*)d_in[5];
    float* outf = (float*)d_out;
    (void)in_sizes; (void)n_in; (void)out_size;

    const size_t PLANES_BYTES = 60ull * IMGC_ * sizeof(h2);   // 31,457,280
    const size_t KREV_BYTES   = 25ull * G_ * G_ * sizeof(h2); // 26,214,400

    if (d_ws != nullptr && ws_size >= PLANES_BYTES + KREV_BYTES) {
        h2* P    = (h2*)d_ws;
        h2* Krev = (h2*)((char*)d_ws + PLANES_BYTES);
        zeroF<<<OUTF_ / 256, 256, 0, stream>>>(outf, 0);
        kernelR<<<25 * 512, 256, 0, stream>>>(kr, ki, Krev);
        for (int n = 0; n < N_; n++) {
            kernelA2<<<C_ * A_ * 32, 256, 0, stream>>>(xr, xi, mr, mi, P, n);
            kernelB2<<<C_ * 512, 320, 0, stream>>>(Krev, P);
            kernelC2<<<C_ * A_ * 32, 256, 0, stream>>>(mr, mi, P, outf, n);
        }
        return;
    }

    // ---- fallback ----
    zeroF<<<HALFF_ / 256, 256, 0, stream>>>(outf, 0);
    {
        h2* X1 = (h2*)(outf + HALFF_);
        h2* X2 = (h2*)(outf + HALFF_ + IMGC_);
        for (int c = 0; c < C_; c++)
            for (int b = 0; b < A_; b++) {
                for (int a = 0; a < A_; a++) {
                    kernelA<<<32, 256, 0, stream>>>(xr, xi, mr, mi, X1, 0, c, a);
                    kernelB<<<512, 256, 0, stream>>>(kr, ki, X1, X2, b, a);
                }
                kernelC<<<32, 256, 0, stream>>>(mr, mi, X2, outf, 0, c, b);
            }
    }

    zeroF<<<HALFF_ / 256, 256, 0, stream>>>(outf, HALFF_);
    {
        h2* X1 = (h2*)d_in[0];
        h2* X2 = (h2*)d_in[1];
        for (int c = 0; c < C_; c++)
            for (int b = 0; b < A_; b++) {
                for (int a = 0; a < A_; a++) {
                    kernelA<<<32, 256, 0, stream>>>(xr, xi, mr, mi, X1, 1, c, a);
                    kernelB<<<512, 256, 0, stream>>>(kr, ki, X1, X2, b, a);
                }
                kernelC<<<32, 256, 0, stream>>>(mr, mi, X2, outf, 1, c, b);
            }
    }
}

// Round 7
// 382.026 us; speedup vs baseline: 1.4791x; 1.4791x over previous
//
#include <hip/hip_runtime.h>
#include <math.h>

#define N_ 2
#define A_ 5
#define C_ 12
#define H_ 256
#define G_ 512
// out = 4 * ifft_ortho(K * fft_ortho(...)) ==> 4/(512*512) on unnormalized FFTs
#define SCALE_ (4.0f / 262144.0f)
#define OUTF_ 655360       // out = fp32 REAL part, [2,5,256,256]
#define HALFF_ 327680      // per-n float count
#define IMGC_ 131072       // 512*256 complex: one spectral half-plane (h2 elems)

// ---- fp16-pair scratch ------------------------------------------------------
struct __attribute__((aligned(4))) h2 { _Float16 x, y; };
struct __attribute__((aligned(8))) h2x2 { _Float16 x0, y0, x1, y1; };
__device__ __forceinline__ float2 ld2(const h2* p, size_t i) {
    h2 v = p[i]; return make_float2((float)v.x, (float)v.y);
}
__device__ __forceinline__ void st2(h2* p, size_t i, float2 v) {
    float x = fminf(fmaxf(v.x, -60000.f), 60000.f);   // never store inf
    float y = fminf(fmaxf(v.y, -60000.f), 60000.f);
    h2 o; o.x = (_Float16)x; o.y = (_Float16)y; p[i] = o;
}

__device__ __forceinline__ float2 cmul(float2 a, float2 b) {
    return make_float2(a.x * b.x - a.y * b.y, a.x * b.y + a.y * b.x);
}

// ---- float4 = two adjacent complexes helpers --------------------------------
__device__ __forceinline__ float4 qadd(float4 a, float4 b) {
    return make_float4(a.x + b.x, a.y + b.y, a.z + b.z, a.w + b.w);
}
__device__ __forceinline__ float4 qsub(float4 a, float4 b) {
    return make_float4(a.x - b.x, a.y - b.y, a.z - b.z, a.w - b.w);
}
__device__ __forceinline__ float4 qmul(float4 a, float4 w) {   // per-complex a*w
    return make_float4(a.x * w.x - a.y * w.y, a.x * w.y + a.y * w.x,
                       a.z * w.z - a.w * w.w, a.z * w.w + a.w * w.z);
}
__device__ __forceinline__ float4 qmulc(float4 a, float4 w) {  // per-complex a*conj(w)
    return make_float4(a.x * w.x + a.y * w.y, a.y * w.x - a.x * w.y,
                       a.z * w.z + a.w * w.w, a.w * w.z - a.z * w.w);
}
// f4-index bank swizzle: bijective within 8-blocks, kills stride-4/16 conflicts
__device__ __forceinline__ int PHI(int i) { return i ^ ((i >> 3) & 7); }

// Per-stage twiddle tables, float2 twS[512]:
//   stage half-size m occupies f2 [off, off+m), off = 0,256,384,448,480,496,
//   504,508,510; entry j = w^(j*(256/m)), w = exp(-2pi i/512).
__device__ __forceinline__ void build_twS(float2* twS, int t) {
    if (t < 256) {
        float s, c;
        sincosf(-6.283185307179586f * (float)t * (1.0f / 512.0f), &s, &c);
        twS[t] = make_float2(c, s);
    }
    __syncthreads();
    int off = 256;
    #pragma unroll
    for (int sh = 1; sh <= 8; sh++) {
        int sz = 256 >> sh;
        if (t < sz) twS[off + t] = twS[t << sh];
        off += sz;
    }
    __syncthreads();
}

// ---- radix-4 f4-paired LDS quads (proven R5 form) ---------------------------
__device__ __forceinline__ void fwd_quad(float4* D, const float4* tw4,
                                         int bt, int M4, int offA4) {
    int jf = bt & (M4 - 1);
    int f0 = ((bt & ~(M4 - 1)) << 2) | jf;
    float4 x0 = D[PHI(f0)],          x1 = D[PHI(f0 + M4)];
    float4 x2 = D[PHI(f0 + 2 * M4)], x3 = D[PHI(f0 + 3 * M4)];
    float4 tA  = tw4[offA4 + jf];
    float4 tA2 = tw4[offA4 + M4 + jf];
    float4 tB  = tw4[offA4 + 2 * M4 + jf];
    float4 u0 = qadd(x0, x2), v0 = qmul(qsub(x0, x2), tA);
    float4 u1 = qadd(x1, x3), v1 = qmul(qsub(x1, x3), tA2);
    D[PHI(f0)]          = qadd(u0, u1);
    D[PHI(f0 + M4)]     = qmul(qsub(u0, u1), tB);
    D[PHI(f0 + 2 * M4)] = qadd(v0, v1);
    D[PHI(f0 + 3 * M4)] = qmul(qsub(v0, v1), tB);
}
__device__ __forceinline__ void inv_quad(float4* D, const float4* tw4,
                                         int bt, int M2, int offM4, int off2M4) {
    int jf = bt & (M2 - 1);
    int f0 = ((bt & ~(M2 - 1)) << 2) | jf;
    float4 x0 = D[PHI(f0)],          x1 = D[PHI(f0 + M2)];
    float4 x2 = D[PHI(f0 + 2 * M2)], x3 = D[PHI(f0 + 3 * M2)];
    float4 wA  = tw4[offM4 + jf];
    float4 wB0 = tw4[off2M4 + jf];
    float4 wB1 = tw4[off2M4 + M2 + jf];
    float4 t1 = qmulc(x1, wA), t3 = qmulc(x3, wA);
    float4 u0 = qadd(x0, t1), u1 = qsub(x0, t1);
    float4 u2 = qadd(x2, t3), u3 = qsub(x2, t3);
    float4 s2 = qmulc(u2, wB0), s3 = qmulc(u3, wB1);
    D[PHI(f0)]          = qadd(u0, s2);
    D[PHI(f0 + M2)]     = qadd(u1, s3);
    D[PHI(f0 + 2 * M2)] = qsub(u0, s2);
    D[PHI(f0 + 3 * M2)] = qsub(u1, s3);
}

// ---- legacy single-array radix-2 FFTs (fallback path only) ------------------
__device__ void fft512_dif(float2* d, const float2* twS, int t) {
    int off = 0;
    #pragma unroll
    for (int m = 256; m >= 1; m >>= 1) {
        if (m >= 64) __syncthreads();
        else __builtin_amdgcn_wave_barrier();
        int j = t & (m - 1);
        int p = ((t & ~(m - 1)) << 1) | j;
        int q = p + m;
        float2 a = d[p], b = d[q];
        d[p] = make_float2(a.x + b.x, a.y + b.y);
        float2 s = make_float2(a.x - b.x, a.y - b.y);
        d[q] = cmul(s, twS[off + j]);
        off += m;
    }
    __syncthreads();
}
__device__ void ifft512_dit(float2* d, const float2* twS, int t) {
    int off = 510;
    #pragma unroll
    for (int m = 1; m <= 256; m <<= 1) {
        if (m == 1 || m >= 128) __syncthreads();
        else __builtin_amdgcn_wave_barrier();
        int j = t & (m - 1);
        int p = ((t & ~(m - 1)) << 1) | j;
        int q = p + m;
        float2 w = twS[off + j];
        w.y = -w.y;
        float2 b = cmul(d[q], w);
        float2 a = d[p];
        d[p] = make_float2(a.x + b.x, a.y + b.y);
        d[q] = make_float2(a.x - b.x, a.y - b.y);
        off -= (m << 1);
    }
    __syncthreads();
}

// ---- zero a float range of out ---------------------------------------------
__global__ __launch_bounds__(256)
void zeroF(float* outf, int base) {
    outf[(size_t)base + blockIdx.x * 256 + threadIdx.x] = 0.f;
}

// ===========================================================================
// FAST PATH. P holds nspan*60 half-planes [nl][c][a]; Krev is the
// bit-reversed-w fp16 kernel copy. A2/B2/C2 take (n0, nspan) so one
// dispatch covers both n when ws allows (fewer tails + bubbles).
// ===========================================================================

// R: Krev[p][h][jw] = K[p][h][brev9(jw)], p = b*5+a. grid(25*512).
// Direct bit-reversed gather (2 KB row stays in L1/L2), coalesced stores;
// no LDS (old LDS read pattern was a 32-way bank conflict).
__global__ __launch_bounds__(256)
void kernelR(const float* __restrict__ kr, const float* __restrict__ ki,
             h2* Krev) {
    int p = blockIdx.x >> 9;
    int h = blockIdx.x & 511;
    int t = threadIdx.x;
    size_t base = ((size_t)p * G_ + h) * G_;
    int j0 = __brev((unsigned)t) >> 23;
    int j1 = __brev((unsigned)(t + 256)) >> 23;
    st2(Krev, base + t,       make_float2(kr[base + j0], ki[base + j0]));
    st2(Krev, base + t + 256, make_float2(kr[base + j1], ki[base + j1]));
}

// A2: x*mps, pad h, fwd FFT_h (radix-4 f4, wave owns 2 rows, mm=1 fused into
// transposed store), store to P[nl,c,a]. grid(nspan*12*5*32), 256 thr.
__global__ __launch_bounds__(256)
void kernelA2(const float* __restrict__ xr, const float* __restrict__ xi,
              const float* __restrict__ mr, const float* __restrict__ mi,
              h2* P, int n0, int nspan) {
    int blk = blockIdx.x;
    int oct = blk & 31;
    int a   = (blk >> 5) % 5;
    int rest = blk / 160;
    int c  = rest % 12;
    int nl = rest / 12;
    int n  = n0 + nl;
    int t = threadIdx.x;
    __shared__ float2 twS[512];
    __shared__ float4 rows4[8][262];
    build_twS(twS, t);
    const float4* tw4 = (const float4*)twS;

    int r = t & 7;
    int wc = oct * 8 + r;
    float2* rowf2 = (float2*)&rows4[r][0];
    #pragma unroll
    for (int k = 0; k < 8; k++) {
        int h = (t >> 3) + 32 * k;
        size_t xo = (((size_t)n * A_ + a) * H_ + h) * H_ + wc;
        size_t mo = (((size_t)c) * H_ + h) * H_ + wc;
        float xr_ = xr[xo], xi_ = xi[xo];
        float mr_ = mr[mo], mi_ = mi[mo];
        int e = h + 128;
        rowf2[2 * PHI(e >> 1) + (e & 1)] =
            make_float2(xr_ * mr_ - xi_ * mi_, xr_ * mi_ + xi_ * mr_);
        int z = (h < 128) ? h : (h + 256);
        rowf2[2 * PHI(z >> 1) + (z & 1)] = make_float2(0.f, 0.f);
    }
    __syncthreads();

    int wv = t >> 6, ln = t & 63;
    float4* d0 = &rows4[2 * wv][0];
    float4* d1 = &rows4[2 * wv + 1][0];
    fwd_quad(d0, tw4, ln, 64, 0);   fwd_quad(d1, tw4, ln, 64, 0);
    __builtin_amdgcn_wave_barrier();
    fwd_quad(d0, tw4, ln, 16, 192); fwd_quad(d1, tw4, ln, 16, 192);
    __builtin_amdgcn_wave_barrier();
    fwd_quad(d0, tw4, ln, 4, 240);  fwd_quad(d1, tw4, ln, 4, 240);
    __builtin_amdgcn_wave_barrier();
    fwd_quad(d0, tw4, ln, 1, 252);  fwd_quad(d1, tw4, ln, 1, 252);
    __syncthreads();

    h2* Pp = P + (size_t)((nl * 12 + c) * 5 + a) * IMGC_;
    #pragma unroll
    for (int k = 0; k < 16; k++) {
        int jh = k * 32 + (t >> 3);
        float4 v = rows4[r][PHI(jh >> 1)];
        float2 res = (jh & 1) ? make_float2(v.x - v.z, v.y - v.w)
                              : make_float2(v.x + v.z, v.y + v.w);
        st2(Pp, (size_t)jh * 256 + oct * 8 + r, res);
    }
}

// B2: 320 thr, wave w owns array a=w (load, fwd FFT) and b=w (inv FFT, store);
// mix is pointwise per f4-column -> in-place, 4 syncthreads total.
// grid 8 XCD chunks x (64 jh x 12 c x nspan): xcd = blk&7 owns jh in
// [64*xcd, 64*xcd+64) so each XCD's L2 sees only 3.3 MB of Krev.
__global__ __launch_bounds__(320)
void kernelB2(const h2* __restrict__ Krev, h2* P, int nspan) {
    int blk = blockIdx.x;
    int xcd = blk & 7;
    int idx = blk >> 3;
    int cn  = 12 * nspan;
    int jh  = xcd * 64 + idx / cn;
    int rem = idx % cn;
    int c   = rem % 12;
    int nl  = rem / 12;
    int htrue = __brev((unsigned)jh) >> 23;
    int t = threadIdx.x;
    __shared__ float2 twS[512];
    __shared__ float4 Fa4[5][256];
    build_twS(twS, t);
    const float4* tw4 = (const float4*)twS;
    int wv = t >> 6, ln = t & 63;
    size_t pbase = (size_t)((nl * 12 + c) * 5) * IMGC_ + (size_t)jh * 256;

    // wave w loads array a=w (centered pad in w-dim)
    float2* Ff2 = (float2*)&Fa4[wv][0];
    const h2* Pa = P + pbase + (size_t)wv * IMGC_;
    #pragma unroll
    for (int k = 0; k < 4; k++) {
        int e = ln + 64 * k;
        float2 v = ld2(Pa, e);
        int ec = e + 128;
        Ff2[2 * PHI(ec >> 1) + (ec & 1)] = v;
        int z = (e < 128) ? e : (e + 256);
        Ff2[2 * PHI(z >> 1) + (z & 1)] = make_float2(0.f, 0.f);
    }
    __builtin_amdgcn_wave_barrier();

    float4* D = &Fa4[wv][0];
    fwd_quad(D, tw4, ln, 64, 0);   __builtin_amdgcn_wave_barrier();
    fwd_quad(D, tw4, ln, 16, 192); __builtin_amdgcn_wave_barrier();
    fwd_quad(D, tw4, ln, 4, 240);  __builtin_amdgcn_wave_barrier();
    fwd_quad(D, tw4, ln, 1, 252);
    __syncthreads();   // all 5 arrays' forward FFTs done

    if (t < 256) {
        // fused fwd mm=1 on read: F[2t] = e0+e1, F[2t+1] = e0-e1
        float2 f0[5], f1[5];
        #pragma unroll
        for (int a = 0; a < 5; a++) {
            float4 x = Fa4[a][PHI(t)];
            f0[a] = make_float2(x.x + x.z, x.y + x.w);
            f1[a] = make_float2(x.x - x.z, x.y - x.w);
        }
        const h2x2* Kp = reinterpret_cast<const h2x2*>(Krev);
        #pragma unroll
        for (int b = 0; b < 5; b++) {
            float2 a0 = make_float2(0.f, 0.f);
            float2 a1 = make_float2(0.f, 0.f);
            #pragma unroll
            for (int a = 0; a < 5; a++) {
                h2x2 kv = Kp[((size_t)(b * 5 + a) * G_ + htrue) * 256 + t];
                float k0x = (float)kv.x0, k0y = (float)kv.y0;
                float k1x = (float)kv.x1, k1y = (float)kv.y1;
                a0.x += k0x * f0[a].x - k0y * f0[a].y;
                a0.y += k0x * f0[a].y + k0y * f0[a].x;
                a1.x += k1x * f1[a].x - k1y * f1[a].y;
                a1.y += k1x * f1[a].y + k1y * f1[a].x;
            }
            // fused inv mm=1 on write: (a0+a1, a0-a1) in place over Fa
            Fa4[b][PHI(t)] =
                make_float4(a0.x + a1.x, a0.y + a1.y, a0.x - a1.x, a0.y - a1.y);
        }
    }
    __syncthreads();   // mix writes visible

    inv_quad(D, tw4, ln, 1, 254, 252);  __builtin_amdgcn_wave_barrier();
    inv_quad(D, tw4, ln, 4, 248, 240);  __builtin_amdgcn_wave_barrier();
    inv_quad(D, tw4, ln, 16, 224, 192); __builtin_amdgcn_wave_barrier();
    inv_quad(D, tw4, ln, 64, 128, 0);
    __builtin_amdgcn_wave_barrier();

    // wave w stores b=w (crop w-dim)
    h2* Pb = P + pbase + (size_t)wv * IMGC_;
    #pragma unroll
    for (int k = 0; k < 4; k++) {
        int e = ln + 64 * k;
        int ec = e + 128;
        float2 v = Ff2[2 * PHI(ec >> 1) + (ec & 1)];
        st2(Pb, e, v);
    }
}

// C2: inv FFT_h of P[nl,c,b] (radix-4 f4, wave owns 2 rows, mm=1 fused into
// load), crop h, Re(conj(mps)*y)*scale, fp32 atomics. grid(nspan*12*5*32).
__global__ __launch_bounds__(256)
void kernelC2(const float* __restrict__ mr, const float* __restrict__ mi,
              const h2* __restrict__ P, float* outf, int n0, int nspan) {
    int blk = blockIdx.x;
    int oct = blk & 31;
    int b   = (blk >> 5) % 5;
    int rest = blk / 160;
    int c  = rest % 12;
    int nl = rest / 12;
    int n  = n0 + nl;
    int t = threadIdx.x;
    __shared__ float2 twS[512];
    __shared__ float4 rows4[8][262];
    build_twS(twS, t);
    const float4* tw4 = (const float4*)twS;

    int r = t & 7;
    int wc = oct * 8 + r;
    const h2* Pb = P + (size_t)((nl * 12 + c) * 5 + b) * IMGC_;
    #pragma unroll
    for (int k = 0; k < 8; k++) {
        int jh0 = k * 64 + (t >> 3) * 2;
        float2 p0 = ld2(Pb, (size_t)jh0 * 256 + wc);
        float2 p1 = ld2(Pb, (size_t)(jh0 + 1) * 256 + wc);
        rows4[r][PHI(jh0 >> 1)] =
            make_float4(p0.x + p1.x, p0.y + p1.y, p0.x - p1.x, p0.y - p1.y);
    }
    __syncthreads();

    int wv = t >> 6, ln = t & 63;
    float4* d0 = &rows4[2 * wv][0];
    float4* d1 = &rows4[2 * wv + 1][0];
    inv_quad(d0, tw4, ln, 1, 254, 252);  inv_quad(d1, tw4, ln, 1, 254, 252);
    __builtin_amdgcn_wave_barrier();
    inv_quad(d0, tw4, ln, 4, 248, 240);  inv_quad(d1, tw4, ln, 4, 248, 240);
    __builtin_amdgcn_wave_barrier();
    inv_quad(d0, tw4, ln, 16, 224, 192); inv_quad(d1, tw4, ln, 16, 224, 192);
    __builtin_amdgcn_wave_barrier();
    inv_quad(d0, tw4, ln, 64, 128, 0);   inv_quad(d1, tw4, ln, 64, 128, 0);
    __syncthreads();

    const float2* rowf2 = (const float2*)&rows4[r][0];
    #pragma unroll
    for (int k = 0; k < 8; k++) {
        int hh = (t >> 3) + 32 * k;
        int e = hh + 128;
        float2 v = rowf2[2 * PHI(e >> 1) + (e & 1)];
        size_t mo = (((size_t)c) * H_ + hh) * H_ + wc;
        float m_r = mr[mo], m_i = mi[mo];
        float re = (m_r * v.x + m_i * v.y) * SCALE_;
        size_t idx = (((size_t)n * A_ + b) * H_ + hh) * H_ + wc;
        unsafeAtomicAdd(&outf[idx], re);
    }
}

// ===========================================================================
// FALLBACK PATH (used when ws_size < 57.7 MB)
// ===========================================================================

__global__ __launch_bounds__(256)
void kernelA(const float* __restrict__ xr, const float* __restrict__ xi,
             const float* __restrict__ mr, const float* __restrict__ mi,
             h2* X1, int n, int c, int a) {
    int oct = blockIdx.x;
    int t = threadIdx.x;
    __shared__ float2 twS[512];
    __shared__ float2 rows[8][516];
    build_twS(twS, t);

    int r = t & 7;
    int wc = oct * 8 + r;
    #pragma unroll
    for (int k = 0; k < 8; k++) {
        int h = (t >> 3) + 32 * k;
        size_t xo = (((size_t)n * A_ + a) * H_ + h) * H_ + wc;
        size_t mo = (((size_t)c) * H_ + h) * H_ + wc;
        float xr_ = xr[xo], xi_ = xi[xo];
        float mr_ = mr[mo], mi_ = mi[mo];
        rows[r][h + 128] = make_float2(xr_ * mr_ - xi_ * mi_,
                                       xr_ * mi_ + xi_ * mr_);
        rows[r][(h < 128) ? h : (h + 256)] = make_float2(0.f, 0.f);
    }
    __syncthreads();
    for (int rr = 0; rr < 8; rr++) fft512_dif(&rows[rr][0], twS, t);

    #pragma unroll
    for (int k = 0; k < 16; k++) {
        int jh = k * 32 + (t >> 3);
        st2(X1, (size_t)jh * 256 + oct * 8 + (t & 7), rows[t & 7][jh]);
    }
}

__global__ __launch_bounds__(256)
void kernelB(const float* __restrict__ kr, const float* __restrict__ ki,
             const h2* X1, h2* X2, int b, int a) {
    int jh = blockIdx.x;
    int htrue = __brev((unsigned)jh) >> 23;
    int t = threadIdx.x;
    __shared__ float2 twS[512];
    __shared__ float2 F[512];
    __shared__ float2 g[512];
    build_twS(twS, t);

    float2 v = ld2(X1, (size_t)jh * 256 + t);
    F[t + 128] = v;
    F[(t < 128) ? t : (t + 256)] = make_float2(0.f, 0.f);
    __syncthreads();
    fft512_dif(F, twS, t);

    #pragma unroll
    for (int half = 0; half < 2; half++) {
        int jw = t + half * 256;
        int wtrue = __brev((unsigned)jw) >> 23;
        size_t kidx = (((size_t)(b * A_ + a)) * G_ + htrue) * G_ + wtrue;
        g[jw] = cmul(make_float2(kr[kidx], ki[kidx]), F[jw]);
    }
    ifft512_dit(g, twS, t);

    float2 res = g[t + 128];
    size_t o = (size_t)jh * 256 + t;
    if (a == 0) st2(X2, o, res);
    else {
        float2 cur = ld2(X2, o);
        st2(X2, o, make_float2(cur.x + res.x, cur.y + res.y));
    }
}

__global__ __launch_bounds__(256)
void kernelC(const float* __restrict__ mr, const float* __restrict__ mi,
             const h2* X2, float* outf, int n, int c, int b) {
    int oct = blockIdx.x;
    int t = threadIdx.x;
    __shared__ float2 twS[512];
    __shared__ float2 rows[8][516];
    build_twS(twS, t);

    #pragma unroll
    for (int k = 0; k < 16; k++) {
        int jh = k * 32 + (t >> 3);
        rows[t & 7][jh] = ld2(X2, (size_t)jh * 256 + oct * 8 + (t & 7));
    }
    for (int rr = 0; rr < 8; rr++) ifft512_dit(&rows[rr][0], twS, t);

    int r = t & 7;
    int wc = oct * 8 + r;
    #pragma unroll
    for (int k = 0; k < 8; k++) {
        int hh = (t >> 3) + 32 * k;
        float2 v = rows[r][hh + 128];
        size_t mo = (((size_t)c) * H_ + hh) * H_ + wc;
        float m_r = mr[mo], m_i = mi[mo];
        float re = (m_r * v.x + m_i * v.y) * SCALE_;
        size_t idx = (((size_t)n * A_ + b) * H_ + hh) * H_ + wc;
        outf[idx] += re;
    }
}

// ===========================================================================
extern "C" void kernel_launch(void* const* d_in, const int* in_sizes, int n_in,
                              void* d_out, int out_size, void* d_ws, size_t ws_size,
                              hipStream_t stream) {
    const float* xr = (const float*)d_in[0];
    const float* xi = (const float*)d_in[1];
    const float* mr = (const float*)d_in[2];
    const float* mi = (const float*)d_in[3];
    const float* kr = (const float*)d_in[4];
    const float* ki = (const float*)d_in[5];
    float* outf = (float*)d_out;
    (void)in_sizes; (void)n_in; (void)out_size;

    const size_t KREV_BYTES = 25ull * G_ * G_ * sizeof(h2);    // 26,214,400
    const size_t PLANES1    = 60ull * IMGC_ * sizeof(h2);      // 31,457,280
    const size_t PLANES2    = 120ull * IMGC_ * sizeof(h2);     // 62,914,560

    if (d_ws != nullptr && ws_size >= PLANES2 + KREV_BYTES) {
        // ---- fully fused: both n in every dispatch (5 dispatches total)
        h2* P    = (h2*)d_ws;
        h2* Krev = (h2*)((char*)d_ws + PLANES2);
        zeroF<<<OUTF_ / 256, 256, 0, stream>>>(outf, 0);
        kernelR<<<25 * 512, 256, 0, stream>>>(kr, ki, Krev);
        kernelA2<<<2 * C_ * A_ * 32, 256, 0, stream>>>(xr, xi, mr, mi, P, 0, 2);
        kernelB2<<<2 * C_ * 512, 320, 0, stream>>>(Krev, P, 2);
        kernelC2<<<2 * C_ * A_ * 32, 256, 0, stream>>>(mr, mi, P, outf, 0, 2);
        return;
    }

    if (d_ws != nullptr && ws_size >= PLANES1 + KREV_BYTES) {
        // ---- per-n schedule (proven R5 structure)
        h2* P    = (h2*)d_ws;
        h2* Krev = (h2*)((char*)d_ws + PLANES1);
        zeroF<<<OUTF_ / 256, 256, 0, stream>>>(outf, 0);
        kernelR<<<25 * 512, 256, 0, stream>>>(kr, ki, Krev);
        for (int n = 0; n < N_; n++) {
            kernelA2<<<C_ * A_ * 32, 256, 0, stream>>>(xr, xi, mr, mi, P, n, 1);
            kernelB2<<<C_ * 512, 320, 0, stream>>>(Krev, P, 1);
            kernelC2<<<C_ * A_ * 32, 256, 0, stream>>>(mr, mi, P, outf, n, 1);
        }
        return;
    }

    // ---- fallback ----
    zeroF<<<HALFF_ / 256, 256, 0, stream>>>(outf, 0);
    {
        h2* X1 = (h2*)(outf + HALFF_);
        h2* X2 = (h2*)(outf + HALFF_ + IMGC_);
        for (int c = 0; c < C_; c++)
            for (int b = 0; b < A_; b++) {
                for (int a = 0; a < A_; a++) {
                    kernelA<<<32, 256, 0, stream>>>(xr, xi, mr, mi, X1, 0, c, a);
                    kernelB<<<512, 256, 0, stream>>>(kr, ki, X1, X2, b, a);
                }
                kernelC<<<32, 256, 0, stream>>>(mr, mi, X2, outf, 0, c, b);
            }
    }

    zeroF<<<HALFF_ / 256, 256, 0, stream>>>(outf, HALFF_);
    {
        h2* X1 = (h2*)d_in[0];
        h2* X2 = (h2*)d_in[1];
        for (int c = 0; c < C_; c++)
            for (int b = 0; b < A_; b++) {
                for (int a = 0; a < A_; a++) {
                    kernelA<<<32, 256, 0, stream>>>(xr, xi, mr, mi, X1, 1, c, a);
                    kernelB<<<512, 256, 0, stream>>>(kr, ki, X1, X2, b, a);
                }
                kernelC<<<32, 256, 0, stream>>>(mr, mi, X2, outf, 1, c, b);
            }
    }
}